// Round 20
// baseline (137.550 us; speedup 1.0000x reference)
//
#include <hip/hip_runtime.h>
#include <math.h>

// MemoryCenters: sim = q·K^T (1024x100000, D=128), top-32 by rbf=exp(-2*dist_sq),
// softmax(log(rbf+eps)+log(h+eps)), r_V = w·V_sel, r_E = w·e_sel.
//
// Round 20 = Round 19 (coalesced fragment-major reg-streaming, 123.8us) with
// block work split 2x for latency hiding: R19 measured Occupancy 23% < the
// 50% VGPR-84 cap -> resident-parallelism-limited. Now a block covers 64 q
// (grid.y 16) and wave-pair h=w>>1 handles chunk half [h*8,h*8+8) of the
// 512-center range; wave w owns q-rows (w&1)*32. Grid (200,16)=3200 blocks
// = 12.5/CU (2x R19) at identical total work, VGPR, and key layout.
// Waves 0&2 (resp 1&3) share per-q LDS counters: block-local atomics + one
// barrier after init and one before the cnt2 store. Append order across waves
// is nondeterministic but finalize's u64 sort on unique (rbf,idx) keys makes
// d_out deterministic. Tail ranges: empty-half guard.
// convert/thresh/finalize byte-identical to R19.
// ws: 25.6MB Kbf + 256KB Qbf + 4KB thr + 819KB cnt2 + 12.58MB (binsU8|buckets).

#define DDIM    128
#define MSAMPLE 12288
#define NBINS   256
#define TOPK    32
#define NQTOT   1024
#define NGRP    200     // 196 real 512-center ranges + pad to multiple of 8
#define BCAP    15
#define EPSM    0.012f
#define SORTN   1024
#define FINEN   256
#define QSH     17
#define QMASK   0x1FFFFu
#define QMARGIN 200u    // 200/16384 = 0.0122 >= 2*EA(0.004) + 2 quanta

typedef __attribute__((ext_vector_type(8))) short short8;   // 8 bf16 = 4 VGPRs
typedef __attribute__((ext_vector_type(4))) float f32x4;    // mfma C/D frag

__device__ inline unsigned short f2bf(float f) {
    unsigned u = __builtin_bit_cast(unsigned, f);
    return (unsigned short)((u + 0x7FFFu + ((u >> 16) & 1u)) >> 16);
}

// ---------------------------------------------------------------------------
// convert: Q -> row-major bf16; K -> FRAGMENT-MAJOR bf16 (identical to R18/19)
// ---------------------------------------------------------------------------
__global__ __launch_bounds__(256)
void convert_kernel(const float* __restrict__ Qg, const float* __restrict__ Kg,
                    unsigned short* __restrict__ Qbf, unsigned short* __restrict__ Kbf,
                    int nq8, int nk8)
{
    int total = nq8 + nk8;
    for (int i = blockIdx.x * 256 + threadIdx.x; i < total; i += gridDim.x * 256) {
        const float* s; int j;
        if (i < nq8) { s = Qg; j = i; }
        else         { s = Kg; j = i - nq8; }
        float4 a = *reinterpret_cast<const float4*>(s + (size_t)j * 8);
        float4 b = *reinterpret_cast<const float4*>(s + (size_t)j * 8 + 4);
        short8 o;
        o[0] = (short)f2bf(a.x); o[1] = (short)f2bf(a.y);
        o[2] = (short)f2bf(a.z); o[3] = (short)f2bf(a.w);
        o[4] = (short)f2bf(b.x); o[5] = (short)f2bf(b.y);
        o[6] = (short)f2bf(b.z); o[7] = (short)f2bf(b.w);
        if (i < nq8) {
            *reinterpret_cast<short8*>(Qbf + (size_t)j * 8) = o;
        } else {
            int row = j >> 4, m = j & 15;
            size_t dest = (size_t)(row >> 5) * 4096
                        + (size_t)((m >> 2) * 2 + ((row >> 4) & 1)) * 512
                        + (size_t)((m & 3) * 16 + (row & 15)) * 8;
            *reinterpret_cast<short8*>(Kbf + dest) = o;
        }
    }
}

// ---------------------------------------------------------------------------
// Barrier-light register-streaming bf16 MFMA sim pass (fragment-major Kbf).
// Block = 64 q x one 512-center range; wave w: q-rows (w&1)*32, chunk half
// h=w>>1 ([h*8, h*8+8)). Per chunk: 8 coalesced 1KB fragment loads + 16 MFMA
// + epilogue. MODE 0: u8 bins over [-0.5,0.5]. MODE 1: bucket-append keys.
// ---------------------------------------------------------------------------
template<int MODE>
__global__ __launch_bounds__(256)
void sim_pass(const unsigned short* __restrict__ Qb, const unsigned short* __restrict__ Kb,
              int N, unsigned char* __restrict__ binsU8,
              const float* __restrict__ thr,
              int* __restrict__ cnt2, unsigned int* __restrict__ buckets)
{
    __shared__ int off_l[64];             // per-q counters (shared by wave pair)
    const int tid  = threadIdx.x;
    const int lane = tid & 63;
    const int w    = tid >> 6;            // wave 0..3
    const int lr   = lane & 15;
    const int lk   = lane >> 4;           // 0..3
    const int r    = blockIdx.x;          // center range id (512 centers)
    const int qb64 = blockIdx.y * 64;     // block's 64 q rows
    const int qbase = qb64 + (w & 1) * 32;   // wave's 32 q rows
    const int h    = w >> 1;              // chunk half 0/1
    const int rangeBase = r * 512;

    if (MODE == 1 && rangeBase >= N) return;       // pad ranges (cnt2 pre-zeroed)
    const int totChunks = N >> 5;                  // 3125 (N = 100000 exactly)
    const int ch0 = r * 16;
    const int nch = (MODE == 0) ? 16 : min(16, totChunks - ch0);
    const int tlo = h * 8;
    const int thi = min(nch, tlo + 8);

    // ---- resident A fragments: af[fm][ks] = 8 short8 = 32 VGPR ----
    short8 af[2][4];
    #pragma unroll
    for (int fm = 0; fm < 2; ++fm)
        #pragma unroll
        for (int ks = 0; ks < 4; ++ks)
            af[fm][ks] = *reinterpret_cast<const short8*>(
                Qb + (size_t)(qbase + fm * 16 + lr) * DDIM + (ks * 4 + lk) * 8);

    float thrv[2][4];
    if (MODE == 1) {
        #pragma unroll
        for (int fm = 0; fm < 2; ++fm)
            #pragma unroll
            for (int j = 0; j < 4; ++j)
                thrv[fm][j] = thr[qbase + fm * 16 + lk * 4 + j] - EPSM;
        if (tid < 64) off_l[tid] = 0;
        __syncthreads();                  // counters visible to both wave pairs
    }

#define LOADBG(dst, cc) do {                                                   \
    const unsigned short* base_ = Kb + (size_t)(cc) * 4096 + lane * 8;         \
    _Pragma("unroll")                                                          \
    for (int ks_ = 0; ks_ < 4; ++ks_)                                          \
        _Pragma("unroll")                                                      \
        for (int fn_ = 0; fn_ < 2; ++fn_)                                      \
            dst[fn_][ks_] = *reinterpret_cast<const short8*>(                  \
                base_ + (ks_ * 2 + fn_) * 512);                                \
} while (0)

#define COMPUTE(bgX, tt) do {                                                  \
    const int cbase_ = rangeBase + (tt) * 32;                                  \
    const f32x4 z_ = {0.f, 0.f, 0.f, 0.f};                                     \
    f32x4 acc[2][2];                                                           \
    _Pragma("unroll")                                                          \
    for (int a_ = 0; a_ < 2; ++a_)                                             \
        _Pragma("unroll")                                                      \
        for (int b_ = 0; b_ < 2; ++b_) acc[a_][b_] = z_;                       \
    _Pragma("unroll")                                                          \
    for (int ks_ = 0; ks_ < 4; ++ks_)                                          \
        _Pragma("unroll")                                                      \
        for (int fm_ = 0; fm_ < 2; ++fm_)                                      \
            _Pragma("unroll")                                                  \
            for (int fn_ = 0; fn_ < 2; ++fn_)                                  \
                acc[fm_][fn_] = __builtin_amdgcn_mfma_f32_16x16x32_bf16(       \
                    af[fm_][ks_], bgX[fn_][ks_], acc[fm_][fn_], 0, 0, 0);      \
    /* epilogue — C/D map: col = lane&15, row = (lane>>4)*4 + reg [m89/m91] */ \
    _Pragma("unroll")                                                          \
    for (int fm_ = 0; fm_ < 2; ++fm_) {                                        \
        _Pragma("unroll")                                                      \
        for (int j_ = 0; j_ < 4; ++j_) {                                       \
            const int qlw = fm_ * 16 + lk * 4 + j_;   /* 0..31 within wave */  \
            if (MODE == 0) {                                                   \
                _Pragma("unroll")                                              \
                for (int fn_ = 0; fn_ < 2; ++fn_) {                            \
                    const int c_ = cbase_ + fn_ * 16 + lr;                     \
                    float s_ = acc[fm_][fn_][j_];                              \
                    int b_ = (int)((s_ + 0.5f) * 256.0f);  /* [-0.5,0.5] */    \
                    b_ = b_ < 0 ? 0 : (b_ > NBINS - 1 ? NBINS - 1 : b_);       \
                    binsU8[(size_t)(qbase + qlw) * MSAMPLE + c_] =             \
                        (unsigned char)b_;                                     \
                }                                                              \
            } else {                                                           \
                const float t_ = thrv[fm_][j_];                                \
                const float s0_ = acc[fm_][0][j_], s1_ = acc[fm_][1][j_];      \
                if (__any(fmaxf(s0_, s1_) >= t_)) {                            \
                    _Pragma("unroll")                                          \
                    for (int fn_ = 0; fn_ < 2; ++fn_) {                        \
                        const int c_ = cbase_ + fn_ * 16 + lr;                 \
                        const float s_ = fn_ ? s1_ : s0_;                      \
                        if (s_ >= t_) {   /* c_ < N always (exact chunks) */   \
                            int qs_ = (int)((s_ + 1.0f) * 16384.0f);           \
                            qs_ = qs_ < 0 ? 0 : (qs_ > 32767 ? 32767 : qs_);   \
                            unsigned key_ = ((unsigned)qs_ << QSH)             \
                                          | (~(unsigned)c_ & QMASK);           \
                            int p_ = atomicAdd(&off_l[(w & 1) * 32 + qlw], 1); \
                            if (p_ < BCAP)                                     \
                                buckets[((size_t)(qbase + qlw) * NGRP + r)     \
                                        * BCAP + p_] = key_;                   \
                        }                                                      \
                    }                                                          \
                }                                                              \
            }                                                                  \
        }                                                                      \
    }                                                                          \
} while (0)

    if (thi > tlo) {
        short8 bgA[2][4], bgB[2][4];
        LOADBG(bgA, ch0 + tlo);
        int t = tlo;
        for (; t + 2 <= thi; t += 2) {
            LOADBG(bgB, ch0 + t + 1);
            COMPUTE(bgA, t);
            if (t + 2 < thi) LOADBG(bgA, ch0 + t + 2);
            COMPUTE(bgB, t + 1);
        }
        if (t < thi) COMPUTE(bgA, t);      // odd tail (last real range)
    }
#undef LOADBG
#undef COMPUTE

    if (MODE == 1) {
        __syncthreads();                  // all appends done
        if (tid < 64)
            cnt2[(size_t)(qb64 + tid) * NGRP + r] = min(off_l[tid], BCAP);
    }
}

// ---------------------------------------------------------------------------
// thresh with per-wave sub-histograms; bins over [-0.5,0.5] (identical to R19)
// ---------------------------------------------------------------------------
__global__ __launch_bounds__(256)
void thresh_kernel(const unsigned char* __restrict__ bins, float* __restrict__ thr)
{
    __shared__ int hS[4 * NBINS];
    __shared__ int hA[NBINS];
    __shared__ int hB[NBINS];
    __shared__ int best;
    const int q = blockIdx.x, tid = threadIdx.x;
    const int wv = tid >> 6;
    for (int i = tid; i < 4 * NBINS; i += 256) hS[i] = 0;
    if (tid == 0) best = 0;
    __syncthreads();
    const uint4* bp = reinterpret_cast<const uint4*>(bins + (size_t)q * MSAMPLE);
    int* hw = hS + wv * NBINS;
    for (int i = tid; i < MSAMPLE / 16; i += 256) {
        uint4 v = bp[i];
        unsigned xs[4] = {v.x, v.y, v.z, v.w};
        #pragma unroll
        for (int k = 0; k < 4; ++k) {
            unsigned x = xs[k];
            atomicAdd(&hw[x & 255], 1); x >>= 8;
            atomicAdd(&hw[x & 255], 1); x >>= 8;
            atomicAdd(&hw[x & 255], 1); x >>= 8;
            atomicAdd(&hw[x & 255], 1);
        }
    }
    __syncthreads();
    for (int i = tid; i < NBINS; i += 256)
        hA[i] = hS[i] + hS[NBINS + i] + hS[2 * NBINS + i] + hS[3 * NBINS + i];
    __syncthreads();
    int* src = hA; int* dst = hB;
    for (int off = 1; off < NBINS; off <<= 1) {
        for (int i = tid; i < NBINS; i += 256)
            dst[i] = src[i] + ((i + off < NBINS) ? src[i + off] : 0);
        __syncthreads();
        int* tmp = src; src = dst; dst = tmp;
    }
    for (int i = tid; i < NBINS; i += 256)
        if (src[i] >= TOPK) atomicMax(&best, i);
    __syncthreads();
    if (tid == 0)
        thr[q] = (float)(best - 1) * (1.0f / 256.0f) - 0.5f;   // lower edge - 1 bin
}

// ---------------------------------------------------------------------------
// Finalize (identical to R19): compact unsorted (200 groups, 4-wave scan) ->
// 256-bin histogram rank-selection -> exact fp32 rbf for head set ->
// 256-wide u64 bitonic (rbf desc, idx asc = jax.lax.top_k) -> weights, gathers.
// ---------------------------------------------------------------------------
__global__ __launch_bounds__(256)
void finalize_kernel(const unsigned int* __restrict__ buckets, const int* __restrict__ cnt2,
                     const float* __restrict__ Qg, const float* __restrict__ Kg,
                     const float* __restrict__ V, const float* __restrict__ hIn,
                     const float* __restrict__ eIn,
                     float* __restrict__ out, int N)
{
    __shared__ float qv[DDIM];
    __shared__ unsigned sk[SORTN];
    __shared__ unsigned fk[FINEN];
    __shared__ unsigned long long sk64[FINEN];
    __shared__ int hA[NBINS];
    __shared__ int hB[NBINS];
    __shared__ int cnts[NGRP], offs[NGRP];
    __shared__ int wpart[4];
    __shared__ int bestb, nsel;
    __shared__ float selV[TOPK];
    __shared__ int   selI[TOPK];
    __shared__ float wts[TOPK];
    const int q = blockIdx.x, tid = threadIdx.x;

    if (tid < DDIM) qv[tid] = Qg[(size_t)q * DDIM + tid];
    if (tid < NGRP) cnts[tid] = cnt2[q * NGRP + tid];
    for (int i = tid; i < SORTN; i += 256) sk[i] = 0u;
    if (tid < NBINS) hA[tid] = 0;
    if (tid < FINEN) sk64[tid] = 0ull;
    if (tid == 0) { bestb = 0; nsel = 0; }
    __syncthreads();
    int cv = 0, xv = 0;
    if (tid < NGRP) {
        cv = cnts[tid];
        xv = cv;
        #pragma unroll
        for (int o = 1; o < 64; o <<= 1) {
            int y = __shfl_up(xv, o);
            if ((tid & 63) >= o) xv += y;
        }
        if ((tid & 63) == 63) wpart[tid >> 6] = xv;
    }
    __syncthreads();
    if (tid < NGRP) {
        int add = 0;
        const int myw = tid >> 6;
        #pragma unroll
        for (int ww = 0; ww < 3; ++ww)
            if (ww < myw) add += wpart[ww];
        offs[tid] = xv - cv + add;
    }
    __syncthreads();
    for (int flat = tid; flat < NGRP * BCAP; flat += 256) {
        int gg = flat / BCAP, j = flat - gg * BCAP;
        if (j < cnts[gg]) {
            int dst = offs[gg] + j;
            if (dst < SORTN)
                sk[dst] = buckets[((size_t)q * NGRP + gg) * BCAP + j];
        }
    }
    __syncthreads();
    for (int i = tid; i < SORTN; i += 256) {
        unsigned k = sk[i];
        if (k) atomicAdd(&hA[k >> 24], 1);
    }
    __syncthreads();
    {
        int* src = hA; int* dst = hB;
        for (int off = 1; off < NBINS; off <<= 1) {
            for (int i = tid; i < NBINS; i += 256)
                dst[i] = src[i] + ((i + off < NBINS) ? src[i + off] : 0);
            __syncthreads();
            int* tmp = src; src = dst; dst = tmp;
        }
        for (int i = tid; i < NBINS; i += 256)
            if (src[i] >= TOPK) atomicMax(&bestb, i);
    }
    __syncthreads();
    const unsigned b32q = (unsigned)bestb << 7;
    const unsigned cutq = b32q > QMARGIN ? b32q - QMARGIN : 0u;
    const unsigned cutKey = cutq << QSH;
    for (int i = tid; i < SORTN; i += 256) {
        unsigned k = sk[i];
        if (k != 0u && k >= cutKey) {
            int p = atomicAdd(&nsel, 1);
            if (p < FINEN) fk[p] = k;
        }
    }
    __syncthreads();
    const int m = min(nsel, FINEN);
    const int sub = tid & 3, ci = tid >> 2;
    #pragma unroll
    for (int base = 0; base < FINEN; base += 64) {
        int i = base + ci;
        bool act = i < m;
        int c = 0;
        float s = 0.f;
        if (act) {
            c = (int)(~fk[i] & QMASK);
            const float4* k4 = reinterpret_cast<const float4*>(Kg + (size_t)c * DDIM) + sub;
            const float4* q4 = reinterpret_cast<const float4*>(qv) + sub;
            #pragma unroll
            for (int d = 0; d < 8; ++d) {
                float4 kk = k4[d * 4];
                float4 qq = q4[d * 4];
                s = fmaf(qq.x, kk.x, s); s = fmaf(qq.y, kk.y, s);
                s = fmaf(qq.z, kk.z, s); s = fmaf(qq.w, kk.w, s);
            }
        }
        s += __shfl_xor(s, 1); s += __shfl_xor(s, 2);
        if (act && sub == 0) {
            float dist = 2.0f - 2.0f * s;              // reference op order
            float rbf = expf(dist * -2.0f);            // exp(-dist/(2*0.25))
            sk64[i] = ((unsigned long long)__float_as_uint(rbf) << 32)
                    | (unsigned)(~(unsigned)c);        // rbf desc, then idx asc
        }
    }
    __syncthreads();
    for (int k = 2; k <= FINEN; k <<= 1) {
        for (int j = k >> 1; j > 0; j >>= 1) {
            int x = tid ^ j;
            if (x > tid) {
                unsigned long long a = sk64[tid], b = sk64[x];
                bool sw = ((tid & k) == 0) ? (a < b) : (a > b);
                if (sw) { sk64[tid] = b; sk64[x] = a; }
            }
            __syncthreads();
        }
    }
    if (tid < TOPK) {
        unsigned long long kk = sk64[tid];
        float rbf = __uint_as_float((unsigned)(kk >> 32));
        int   idx = (int)(~(unsigned)kk);
        selV[tid] = rbf; selI[tid] = idx;
        float lw = logf(rbf + 1e-8f) + logf(hIn[idx] + 1e-8f);
        float mx = lw;
        #pragma unroll
        for (int o = 16; o > 0; o >>= 1) mx = fmaxf(mx, __shfl_xor(mx, o));
        float ex = expf(lw - mx);
        float sm = ex;
        #pragma unroll
        for (int o = 16; o > 0; o >>= 1) sm += __shfl_xor(sm, o);
        wts[tid] = ex / sm;
    }
    __syncthreads();
    {
        float acc = 0.f;
        const int v = tid;
        #pragma unroll
        for (int k = 0; k < TOPK; ++k)
            acc = fmaf(wts[k], V[(size_t)selI[k] * 256 + v], acc);
        out[(size_t)q * 256 + v] = acc;
    }
    const int offE = NQTOT * 256;
    const int offW = offE + NQTOT * 4;
    const int offI = offW + NQTOT * TOPK;
    if (tid < 4) {
        float acc = 0.f;
        #pragma unroll
        for (int k = 0; k < TOPK; ++k)
            acc = fmaf(wts[k], eIn[(size_t)selI[k] * 4 + tid], acc);
        out[offE + q * 4 + tid] = acc;
    }
    if (tid < TOPK) {
        out[offW + q * TOPK + tid] = wts[tid];
        out[offI + q * TOPK + tid] = (float)selI[tid];
    }
}

// ---------------------------------------------------------------------------
extern "C" void kernel_launch(void* const* d_in, const int* in_sizes, int n_in,
                              void* d_out, int out_size, void* d_ws, size_t ws_size,
                              hipStream_t stream)
{
    (void)n_in; (void)out_size; (void)ws_size;
    const float* Qg = (const float*)d_in[0];
    const float* Kg = (const float*)d_in[1];
    const float* Vg = (const float*)d_in[2];
    const float* hg = (const float*)d_in[3];
    const float* eg = (const float*)d_in[4];
    const int N = in_sizes[1] / DDIM;          // 100000

    char* w = (char*)d_ws;
    unsigned short* Kbf = (unsigned short*)w;  w += (size_t)N * DDIM * 2;      // 25.6MB (fragment-major)
    unsigned short* Qbf = (unsigned short*)w;  w += (size_t)NQTOT * DDIM * 2;  // 256KB
    float* thr = (float*)w;                    w += NQTOT * 4;                 // 4KB
    int*   cnt2 = (int*)w;                     w += (size_t)NQTOT * NGRP * 4;  // 819KB
    unsigned char* binsU8 = (unsigned char*)w;                                 // 12.58MB
    unsigned int*  buckets = (unsigned int*)w; // aliases binsU8 (12.29MB used)

    hipMemsetAsync(cnt2, 0, (size_t)NQTOT * NGRP * 4, stream);

    dim3 blk(256);
    convert_kernel<<<dim3(2048), blk, 0, stream>>>(
        Qg, Kg, Qbf, Kbf, NQTOT * DDIM / 8, N * DDIM / 8);
    sim_pass<0><<<dim3(MSAMPLE / 512, NQTOT / 64), blk, 0, stream>>>(
        Qbf, Kbf, N, binsU8, nullptr, nullptr, nullptr);
    thresh_kernel<<<dim3(NQTOT), blk, 0, stream>>>(binsU8, thr);
    sim_pass<1><<<dim3(NGRP, NQTOT / 64), blk, 0, stream>>>(
        Qbf, Kbf, N, nullptr, thr, cnt2, buckets);
    finalize_kernel<<<dim3(NQTOT), blk, 0, stream>>>(
        buckets, cnt2, Qg, Kg, Vg, hg, eg, (float*)d_out, N);
}

// Round 21
// 135.633 us; speedup vs baseline: 1.0141x; 1.0141x over previous
//
#include <hip/hip_runtime.h>
#include <math.h>

// MemoryCenters: sim = q·K^T (1024x100000, D=128), top-32 by rbf=exp(-2*dist_sq),
// softmax(log(rbf+eps)+log(h+eps)), r_V = w·V_sel, r_E = w·e_sel.
//
// Round 21 = Round 19 (best: 123.8us) + 3-DEEP software pipeline in sim_pass.
// R20's q-split regressed (block churn broke L2 reuse; FETCH doubled). R19's
// 2-deep pipeline covers ~1 chunk (~250cy) of load latency but first-touch K
// lines cost ~900cy (HBM) and L2 hits ~200cy. Now: load chunk t+2 while
// computing t (prologue loads 0,1). Cost: +32 VGPR (af32 + 3x bg32 + acc16
// ~= 145 -> cap 12 waves/CU, still above the measured ~7.4 -> no TLP loss).
// Geometry/keys/thresh/finalize byte-identical to R19: 512-center ranges,
// NGRP 200, BCAP 15, u8 bins over [-0.5,0.5], fragment-major Kbf.
// ws: 25.6MB Kbf + 256KB Qbf + 4KB thr + 819KB cnt2 + 12.58MB (binsU8|buckets).

#define DDIM    128
#define MSAMPLE 12288
#define NBINS   256
#define TOPK    32
#define NQTOT   1024
#define NGRP    200     // 196 real 512-center ranges + pad to multiple of 8
#define BCAP    15
#define EPSM    0.012f
#define SORTN   1024
#define FINEN   256
#define QSH     17
#define QMASK   0x1FFFFu
#define QMARGIN 200u    // 200/16384 = 0.0122 >= 2*EA(0.004) + 2 quanta

typedef __attribute__((ext_vector_type(8))) short short8;   // 8 bf16 = 4 VGPRs
typedef __attribute__((ext_vector_type(4))) float f32x4;    // mfma C/D frag

__device__ inline unsigned short f2bf(float f) {
    unsigned u = __builtin_bit_cast(unsigned, f);
    return (unsigned short)((u + 0x7FFFu + ((u >> 16) & 1u)) >> 16);
}

// ---------------------------------------------------------------------------
// convert: Q -> row-major bf16; K -> FRAGMENT-MAJOR bf16 (identical to R18/19)
// ---------------------------------------------------------------------------
__global__ __launch_bounds__(256)
void convert_kernel(const float* __restrict__ Qg, const float* __restrict__ Kg,
                    unsigned short* __restrict__ Qbf, unsigned short* __restrict__ Kbf,
                    int nq8, int nk8)
{
    int total = nq8 + nk8;
    for (int i = blockIdx.x * 256 + threadIdx.x; i < total; i += gridDim.x * 256) {
        const float* s; int j;
        if (i < nq8) { s = Qg; j = i; }
        else         { s = Kg; j = i - nq8; }
        float4 a = *reinterpret_cast<const float4*>(s + (size_t)j * 8);
        float4 b = *reinterpret_cast<const float4*>(s + (size_t)j * 8 + 4);
        short8 o;
        o[0] = (short)f2bf(a.x); o[1] = (short)f2bf(a.y);
        o[2] = (short)f2bf(a.z); o[3] = (short)f2bf(a.w);
        o[4] = (short)f2bf(b.x); o[5] = (short)f2bf(b.y);
        o[6] = (short)f2bf(b.z); o[7] = (short)f2bf(b.w);
        if (i < nq8) {
            *reinterpret_cast<short8*>(Qbf + (size_t)j * 8) = o;
        } else {
            int row = j >> 4, m = j & 15;
            size_t dest = (size_t)(row >> 5) * 4096
                        + (size_t)((m >> 2) * 2 + ((row >> 4) & 1)) * 512
                        + (size_t)((m & 3) * 16 + (row & 15)) * 8;
            *reinterpret_cast<short8*>(Kbf + dest) = o;
        }
    }
}

// ---------------------------------------------------------------------------
// Barrier-free register-streaming bf16 MFMA sim pass (fragment-major Kbf),
// 3-deep pipelined. Wave = 32 q rows (af[2][4] resident) x one 512-center
// range (16 chunks); per chunk: 8 coalesced 1KB fragment loads + 16 MFMA +
// epilogue. MODE 0: u8 bins over [-0.5,0.5]. MODE 1: bucket-append keys.
// ---------------------------------------------------------------------------
template<int MODE>
__global__ __launch_bounds__(256)
void sim_pass(const unsigned short* __restrict__ Qb, const unsigned short* __restrict__ Kb,
              int N, unsigned char* __restrict__ binsU8,
              const float* __restrict__ thr,
              int* __restrict__ cnt2, unsigned int* __restrict__ buckets)
{
    __shared__ int off_l[128];            // 4 waves x 32 private counters
    const int tid  = threadIdx.x;
    const int lane = tid & 63;
    const int w    = tid >> 6;            // wave 0..3
    const int lr   = lane & 15;
    const int lk   = lane >> 4;           // 0..3
    const int r    = blockIdx.x;          // center range id (512 centers)
    const int qbase = blockIdx.y * 128 + w * 32;   // wave's 32 q rows
    const int rangeBase = r * 512;

    if (MODE == 1 && rangeBase >= N) return;       // pad ranges (cnt2 pre-zeroed)
    const int totChunks = N >> 5;                  // 3125 (N = 100000 exactly)
    const int ch0 = r * 16;
    const int nch = (MODE == 0) ? 16 : min(16, totChunks - ch0);   // 16 or 5

    // ---- resident A fragments: af[fm][ks] = 8 short8 = 32 VGPR ----
    short8 af[2][4];
    #pragma unroll
    for (int fm = 0; fm < 2; ++fm)
        #pragma unroll
        for (int ks = 0; ks < 4; ++ks)
            af[fm][ks] = *reinterpret_cast<const short8*>(
                Qb + (size_t)(qbase + fm * 16 + lr) * DDIM + (ks * 4 + lk) * 8);

    float thrv[2][4];
    if (MODE == 1) {
        #pragma unroll
        for (int fm = 0; fm < 2; ++fm)
            #pragma unroll
            for (int j = 0; j < 4; ++j)
                thrv[fm][j] = thr[qbase + fm * 16 + lk * 4 + j] - EPSM;
        if (lane < 32) off_l[w * 32 + lane] = 0;   // wave-private, no barrier
    }

#define LOADBG(dst, cc) do {                                                   \
    const unsigned short* base_ = Kb + (size_t)(cc) * 4096 + lane * 8;         \
    _Pragma("unroll")                                                          \
    for (int ks_ = 0; ks_ < 4; ++ks_)                                          \
        _Pragma("unroll")                                                      \
        for (int fn_ = 0; fn_ < 2; ++fn_)                                      \
            dst[fn_][ks_] = *reinterpret_cast<const short8*>(                  \
                base_ + (ks_ * 2 + fn_) * 512);                                \
} while (0)

#define COMPUTE(bgX, tt) do {                                                  \
    const int cbase_ = rangeBase + (tt) * 32;                                  \
    const f32x4 z_ = {0.f, 0.f, 0.f, 0.f};                                     \
    f32x4 acc[2][2];                                                           \
    _Pragma("unroll")                                                          \
    for (int a_ = 0; a_ < 2; ++a_)                                             \
        _Pragma("unroll")                                                      \
        for (int b_ = 0; b_ < 2; ++b_) acc[a_][b_] = z_;                       \
    _Pragma("unroll")                                                          \
    for (int ks_ = 0; ks_ < 4; ++ks_)                                          \
        _Pragma("unroll")                                                      \
        for (int fm_ = 0; fm_ < 2; ++fm_)                                      \
            _Pragma("unroll")                                                  \
            for (int fn_ = 0; fn_ < 2; ++fn_)                                  \
                acc[fm_][fn_] = __builtin_amdgcn_mfma_f32_16x16x32_bf16(       \
                    af[fm_][ks_], bgX[fn_][ks_], acc[fm_][fn_], 0, 0, 0);      \
    /* epilogue — C/D map: col = lane&15, row = (lane>>4)*4 + reg [m89/m91] */ \
    _Pragma("unroll")                                                          \
    for (int fm_ = 0; fm_ < 2; ++fm_) {                                        \
        _Pragma("unroll")                                                      \
        for (int j_ = 0; j_ < 4; ++j_) {                                       \
            const int qlw = fm_ * 16 + lk * 4 + j_;   /* 0..31 within wave */  \
            if (MODE == 0) {                                                   \
                _Pragma("unroll")                                              \
                for (int fn_ = 0; fn_ < 2; ++fn_) {                            \
                    const int c_ = cbase_ + fn_ * 16 + lr;                     \
                    float s_ = acc[fm_][fn_][j_];                              \
                    int b_ = (int)((s_ + 0.5f) * 256.0f);  /* [-0.5,0.5] */    \
                    b_ = b_ < 0 ? 0 : (b_ > NBINS - 1 ? NBINS - 1 : b_);       \
                    binsU8[(size_t)(qbase + qlw) * MSAMPLE + c_] =             \
                        (unsigned char)b_;                                     \
                }                                                              \
            } else {                                                           \
                const float t_ = thrv[fm_][j_];                                \
                const float s0_ = acc[fm_][0][j_], s1_ = acc[fm_][1][j_];      \
                if (__any(fmaxf(s0_, s1_) >= t_)) {                            \
                    _Pragma("unroll")                                          \
                    for (int fn_ = 0; fn_ < 2; ++fn_) {                        \
                        const int c_ = cbase_ + fn_ * 16 + lr;                 \
                        const float s_ = fn_ ? s1_ : s0_;                      \
                        if (s_ >= t_) {   /* c_ < N always (exact chunks) */   \
                            int qs_ = (int)((s_ + 1.0f) * 16384.0f);           \
                            qs_ = qs_ < 0 ? 0 : (qs_ > 32767 ? 32767 : qs_);   \
                            unsigned key_ = ((unsigned)qs_ << QSH)             \
                                          | (~(unsigned)c_ & QMASK);           \
                            int p_ = atomicAdd(&off_l[w * 32 + qlw], 1);       \
                            if (p_ < BCAP)                                     \
                                buckets[((size_t)(qbase + qlw) * NGRP + r)     \
                                        * BCAP + p_] = key_;                   \
                        }                                                      \
                    }                                                          \
                }                                                              \
            }                                                                  \
        }                                                                      \
    }                                                                          \
} while (0)

    // 3-deep pipeline: chunks t+1, t+2 in flight while computing t.
    short8 bgA[2][4], bgB[2][4], bgC[2][4];
    LOADBG(bgA, ch0);
    if (nch > 1) LOADBG(bgB, ch0 + 1);
    int t = 0;
    for (; t + 3 <= nch; t += 3) {
        LOADBG(bgC, ch0 + t + 2);
        COMPUTE(bgA, t);
        if (t + 3 < nch) LOADBG(bgA, ch0 + t + 3);
        COMPUTE(bgB, t + 1);
        if (t + 4 < nch) LOADBG(bgB, ch0 + t + 4);
        COMPUTE(bgC, t + 2);
    }
    if (t < nch)     COMPUTE(bgA, t);       // tails: nch=16 -> 1 left; nch=5 -> 2
    if (t + 1 < nch) COMPUTE(bgB, t + 1);
#undef LOADBG
#undef COMPUTE

    if (MODE == 1) {
        if (lane < 32)
            cnt2[(size_t)(qbase + lane) * NGRP + r] =
                min(off_l[w * 32 + lane], BCAP);
    }
}

// ---------------------------------------------------------------------------
// thresh with per-wave sub-histograms; bins over [-0.5,0.5] (identical to R19)
// ---------------------------------------------------------------------------
__global__ __launch_bounds__(256)
void thresh_kernel(const unsigned char* __restrict__ bins, float* __restrict__ thr)
{
    __shared__ int hS[4 * NBINS];
    __shared__ int hA[NBINS];
    __shared__ int hB[NBINS];
    __shared__ int best;
    const int q = blockIdx.x, tid = threadIdx.x;
    const int wv = tid >> 6;
    for (int i = tid; i < 4 * NBINS; i += 256) hS[i] = 0;
    if (tid == 0) best = 0;
    __syncthreads();
    const uint4* bp = reinterpret_cast<const uint4*>(bins + (size_t)q * MSAMPLE);
    int* hw = hS + wv * NBINS;
    for (int i = tid; i < MSAMPLE / 16; i += 256) {
        uint4 v = bp[i];
        unsigned xs[4] = {v.x, v.y, v.z, v.w};
        #pragma unroll
        for (int k = 0; k < 4; ++k) {
            unsigned x = xs[k];
            atomicAdd(&hw[x & 255], 1); x >>= 8;
            atomicAdd(&hw[x & 255], 1); x >>= 8;
            atomicAdd(&hw[x & 255], 1); x >>= 8;
            atomicAdd(&hw[x & 255], 1);
        }
    }
    __syncthreads();
    for (int i = tid; i < NBINS; i += 256)
        hA[i] = hS[i] + hS[NBINS + i] + hS[2 * NBINS + i] + hS[3 * NBINS + i];
    __syncthreads();
    int* src = hA; int* dst = hB;
    for (int off = 1; off < NBINS; off <<= 1) {
        for (int i = tid; i < NBINS; i += 256)
            dst[i] = src[i] + ((i + off < NBINS) ? src[i + off] : 0);
        __syncthreads();
        int* tmp = src; src = dst; dst = tmp;
    }
    for (int i = tid; i < NBINS; i += 256)
        if (src[i] >= TOPK) atomicMax(&best, i);
    __syncthreads();
    if (tid == 0)
        thr[q] = (float)(best - 1) * (1.0f / 256.0f) - 0.5f;   // lower edge - 1 bin
}

// ---------------------------------------------------------------------------
// Finalize (identical to R19): compact unsorted (200 groups, 4-wave scan) ->
// 256-bin histogram rank-selection -> exact fp32 rbf for head set ->
// 256-wide u64 bitonic (rbf desc, idx asc = jax.lax.top_k) -> weights, gathers.
// ---------------------------------------------------------------------------
__global__ __launch_bounds__(256)
void finalize_kernel(const unsigned int* __restrict__ buckets, const int* __restrict__ cnt2,
                     const float* __restrict__ Qg, const float* __restrict__ Kg,
                     const float* __restrict__ V, const float* __restrict__ hIn,
                     const float* __restrict__ eIn,
                     float* __restrict__ out, int N)
{
    __shared__ float qv[DDIM];
    __shared__ unsigned sk[SORTN];
    __shared__ unsigned fk[FINEN];
    __shared__ unsigned long long sk64[FINEN];
    __shared__ int hA[NBINS];
    __shared__ int hB[NBINS];
    __shared__ int cnts[NGRP], offs[NGRP];
    __shared__ int wpart[4];
    __shared__ int bestb, nsel;
    __shared__ float selV[TOPK];
    __shared__ int   selI[TOPK];
    __shared__ float wts[TOPK];
    const int q = blockIdx.x, tid = threadIdx.x;

    if (tid < DDIM) qv[tid] = Qg[(size_t)q * DDIM + tid];
    if (tid < NGRP) cnts[tid] = cnt2[q * NGRP + tid];
    for (int i = tid; i < SORTN; i += 256) sk[i] = 0u;
    if (tid < NBINS) hA[tid] = 0;
    if (tid < FINEN) sk64[tid] = 0ull;
    if (tid == 0) { bestb = 0; nsel = 0; }
    __syncthreads();
    int cv = 0, xv = 0;
    if (tid < NGRP) {
        cv = cnts[tid];
        xv = cv;
        #pragma unroll
        for (int o = 1; o < 64; o <<= 1) {
            int y = __shfl_up(xv, o);
            if ((tid & 63) >= o) xv += y;
        }
        if ((tid & 63) == 63) wpart[tid >> 6] = xv;
    }
    __syncthreads();
    if (tid < NGRP) {
        int add = 0;
        const int myw = tid >> 6;
        #pragma unroll
        for (int ww = 0; ww < 3; ++ww)
            if (ww < myw) add += wpart[ww];
        offs[tid] = xv - cv + add;
    }
    __syncthreads();
    for (int flat = tid; flat < NGRP * BCAP; flat += 256) {
        int gg = flat / BCAP, j = flat - gg * BCAP;
        if (j < cnts[gg]) {
            int dst = offs[gg] + j;
            if (dst < SORTN)
                sk[dst] = buckets[((size_t)q * NGRP + gg) * BCAP + j];
        }
    }
    __syncthreads();
    for (int i = tid; i < SORTN; i += 256) {
        unsigned k = sk[i];
        if (k) atomicAdd(&hA[k >> 24], 1);
    }
    __syncthreads();
    {
        int* src = hA; int* dst = hB;
        for (int off = 1; off < NBINS; off <<= 1) {
            for (int i = tid; i < NBINS; i += 256)
                dst[i] = src[i] + ((i + off < NBINS) ? src[i + off] : 0);
            __syncthreads();
            int* tmp = src; src = dst; dst = tmp;
        }
        for (int i = tid; i < NBINS; i += 256)
            if (src[i] >= TOPK) atomicMax(&bestb, i);
    }
    __syncthreads();
    const unsigned b32q = (unsigned)bestb << 7;
    const unsigned cutq = b32q > QMARGIN ? b32q - QMARGIN : 0u;
    const unsigned cutKey = cutq << QSH;
    for (int i = tid; i < SORTN; i += 256) {
        unsigned k = sk[i];
        if (k != 0u && k >= cutKey) {
            int p = atomicAdd(&nsel, 1);
            if (p < FINEN) fk[p] = k;
        }
    }
    __syncthreads();
    const int m = min(nsel, FINEN);
    const int sub = tid & 3, ci = tid >> 2;
    #pragma unroll
    for (int base = 0; base < FINEN; base += 64) {
        int i = base + ci;
        bool act = i < m;
        int c = 0;
        float s = 0.f;
        if (act) {
            c = (int)(~fk[i] & QMASK);
            const float4* k4 = reinterpret_cast<const float4*>(Kg + (size_t)c * DDIM) + sub;
            const float4* q4 = reinterpret_cast<const float4*>(qv) + sub;
            #pragma unroll
            for (int d = 0; d < 8; ++d) {
                float4 kk = k4[d * 4];
                float4 qq = q4[d * 4];
                s = fmaf(qq.x, kk.x, s); s = fmaf(qq.y, kk.y, s);
                s = fmaf(qq.z, kk.z, s); s = fmaf(qq.w, kk.w, s);
            }
        }
        s += __shfl_xor(s, 1); s += __shfl_xor(s, 2);
        if (act && sub == 0) {
            float dist = 2.0f - 2.0f * s;              // reference op order
            float rbf = expf(dist * -2.0f);            // exp(-dist/(2*0.25))
            sk64[i] = ((unsigned long long)__float_as_uint(rbf) << 32)
                    | (unsigned)(~(unsigned)c);        // rbf desc, then idx asc
        }
    }
    __syncthreads();
    for (int k = 2; k <= FINEN; k <<= 1) {
        for (int j = k >> 1; j > 0; j >>= 1) {
            int x = tid ^ j;
            if (x > tid) {
                unsigned long long a = sk64[tid], b = sk64[x];
                bool sw = ((tid & k) == 0) ? (a < b) : (a > b);
                if (sw) { sk64[tid] = b; sk64[x] = a; }
            }
            __syncthreads();
        }
    }
    if (tid < TOPK) {
        unsigned long long kk = sk64[tid];
        float rbf = __uint_as_float((unsigned)(kk >> 32));
        int   idx = (int)(~(unsigned)kk);
        selV[tid] = rbf; selI[tid] = idx;
        float lw = logf(rbf + 1e-8f) + logf(hIn[idx] + 1e-8f);
        float mx = lw;
        #pragma unroll
        for (int o = 16; o > 0; o >>= 1) mx = fmaxf(mx, __shfl_xor(mx, o));
        float ex = expf(lw - mx);
        float sm = ex;
        #pragma unroll
        for (int o = 16; o > 0; o >>= 1) sm += __shfl_xor(sm, o);
        wts[tid] = ex / sm;
    }
    __syncthreads();
    {
        float acc = 0.f;
        const int v = tid;
        #pragma unroll
        for (int k = 0; k < TOPK; ++k)
            acc = fmaf(wts[k], V[(size_t)selI[k] * 256 + v], acc);
        out[(size_t)q * 256 + v] = acc;
    }
    const int offE = NQTOT * 256;
    const int offW = offE + NQTOT * 4;
    const int offI = offW + NQTOT * TOPK;
    if (tid < 4) {
        float acc = 0.f;
        #pragma unroll
        for (int k = 0; k < TOPK; ++k)
            acc = fmaf(wts[k], eIn[(size_t)selI[k] * 4 + tid], acc);
        out[offE + q * 4 + tid] = acc;
    }
    if (tid < TOPK) {
        out[offW + q * TOPK + tid] = wts[tid];
        out[offI + q * TOPK + tid] = (float)selI[tid];
    }
}

// ---------------------------------------------------------------------------
extern "C" void kernel_launch(void* const* d_in, const int* in_sizes, int n_in,
                              void* d_out, int out_size, void* d_ws, size_t ws_size,
                              hipStream_t stream)
{
    (void)n_in; (void)out_size; (void)ws_size;
    const float* Qg = (const float*)d_in[0];
    const float* Kg = (const float*)d_in[1];
    const float* Vg = (const float*)d_in[2];
    const float* hg = (const float*)d_in[3];
    const float* eg = (const float*)d_in[4];
    const int N = in_sizes[1] / DDIM;          // 100000

    char* w = (char*)d_ws;
    unsigned short* Kbf = (unsigned short*)w;  w += (size_t)N * DDIM * 2;      // 25.6MB (fragment-major)
    unsigned short* Qbf = (unsigned short*)w;  w += (size_t)NQTOT * DDIM * 2;  // 256KB
    float* thr = (float*)w;                    w += NQTOT * 4;                 // 4KB
    int*   cnt2 = (int*)w;                     w += (size_t)NQTOT * NGRP * 4;  // 819KB
    unsigned char* binsU8 = (unsigned char*)w;                                 // 12.58MB
    unsigned int*  buckets = (unsigned int*)w; // aliases binsU8 (12.29MB used)

    hipMemsetAsync(cnt2, 0, (size_t)NQTOT * NGRP * 4, stream);

    dim3 blk(256);
    convert_kernel<<<dim3(2048), blk, 0, stream>>>(
        Qg, Kg, Qbf, Kbf, NQTOT * DDIM / 8, N * DDIM / 8);
    sim_pass<0><<<dim3(MSAMPLE / 512, NQTOT / 128), blk, 0, stream>>>(
        Qbf, Kbf, N, binsU8, nullptr, nullptr, nullptr);
    thresh_kernel<<<dim3(NQTOT), blk, 0, stream>>>(binsU8, thr);
    sim_pass<1><<<dim3(NGRP, NQTOT / 128), blk, 0, stream>>>(
        Qbf, Kbf, N, nullptr, thr, cnt2, buckets);
    finalize_kernel<<<dim3(NQTOT), blk, 0, stream>>>(
        buckets, cnt2, Qg, Kg, Vg, hg, eg, (float*)d_out, N);
}

// Round 22
// 124.126 us; speedup vs baseline: 1.1081x; 1.0927x over previous
//
#include <hip/hip_runtime.h>
#include <math.h>

// MemoryCenters: sim = q·K^T (1024x100000, D=128), top-32 by rbf=exp(-2*dist_sq),
// softmax(log(rbf+eps)+log(h+eps)), r_V = w·V_sel, r_E = w·e_sel.
//
// Round 22 = Round 19 VERBATIM (best measured: 123.8us).
// R16/R20/R21 bracketed the sim-pass design space: occupancy-doubling (LDS
// path), 2x TLP (q-split), and 3-deep ILP all regressed via register pressure
// or L2-churn. R19's point — coalesced fragment-major reg-streaming, 2-deep
// pipeline, VGPR 84, 512-center ranges, grid (200,8) — is the empirical
// optimum. Locking it in.
// ws: 25.6MB Kbf + 256KB Qbf + 4KB thr + 819KB cnt2 + 12.58MB (binsU8|buckets).

#define DDIM    128
#define MSAMPLE 12288
#define NBINS   256
#define TOPK    32
#define NQTOT   1024
#define NGRP    200     // 196 real 512-center ranges + pad to multiple of 8
#define BCAP    15
#define EPSM    0.012f
#define SORTN   1024
#define FINEN   256
#define QSH     17
#define QMASK   0x1FFFFu
#define QMARGIN 200u    // 200/16384 = 0.0122 >= 2*EA(0.004) + 2 quanta

typedef __attribute__((ext_vector_type(8))) short short8;   // 8 bf16 = 4 VGPRs
typedef __attribute__((ext_vector_type(4))) float f32x4;    // mfma C/D frag

__device__ inline unsigned short f2bf(float f) {
    unsigned u = __builtin_bit_cast(unsigned, f);
    return (unsigned short)((u + 0x7FFFu + ((u >> 16) & 1u)) >> 16);
}

// ---------------------------------------------------------------------------
// convert: Q -> row-major bf16; K -> FRAGMENT-MAJOR bf16:
//   chunk = row>>5, fn = (row>>4)&1, lr = row&15, ks = m>>2, lk = m&3
//   dest shorts: chunk*4096 + (ks*2+fn)*512 + (lk*16+lr)*8
// ---------------------------------------------------------------------------
__global__ __launch_bounds__(256)
void convert_kernel(const float* __restrict__ Qg, const float* __restrict__ Kg,
                    unsigned short* __restrict__ Qbf, unsigned short* __restrict__ Kbf,
                    int nq8, int nk8)
{
    int total = nq8 + nk8;
    for (int i = blockIdx.x * 256 + threadIdx.x; i < total; i += gridDim.x * 256) {
        const float* s; int j;
        if (i < nq8) { s = Qg; j = i; }
        else         { s = Kg; j = i - nq8; }
        float4 a = *reinterpret_cast<const float4*>(s + (size_t)j * 8);
        float4 b = *reinterpret_cast<const float4*>(s + (size_t)j * 8 + 4);
        short8 o;
        o[0] = (short)f2bf(a.x); o[1] = (short)f2bf(a.y);
        o[2] = (short)f2bf(a.z); o[3] = (short)f2bf(a.w);
        o[4] = (short)f2bf(b.x); o[5] = (short)f2bf(b.y);
        o[6] = (short)f2bf(b.z); o[7] = (short)f2bf(b.w);
        if (i < nq8) {
            *reinterpret_cast<short8*>(Qbf + (size_t)j * 8) = o;
        } else {
            int row = j >> 4, m = j & 15;
            size_t dest = (size_t)(row >> 5) * 4096
                        + (size_t)((m >> 2) * 2 + ((row >> 4) & 1)) * 512
                        + (size_t)((m & 3) * 16 + (row & 15)) * 8;
            *reinterpret_cast<short8*>(Kbf + dest) = o;
        }
    }
}

// ---------------------------------------------------------------------------
// Barrier-free register-streaming bf16 MFMA sim pass (fragment-major Kbf).
// Wave = 32 q rows (af[2][4] resident) x one 512-center range (16 chunks),
// streamed as 8 coalesced 1KB fragment loads + 16 MFMA + epilogue per chunk.
// MODE 0: u8 bins over [-0.5,0.5]. MODE 1: bucket-append packed keys.
// ---------------------------------------------------------------------------
template<int MODE>
__global__ __launch_bounds__(256)
void sim_pass(const unsigned short* __restrict__ Qb, const unsigned short* __restrict__ Kb,
              int N, unsigned char* __restrict__ binsU8,
              const float* __restrict__ thr,
              int* __restrict__ cnt2, unsigned int* __restrict__ buckets)
{
    __shared__ int off_l[128];            // 4 waves x 32 private counters
    const int tid  = threadIdx.x;
    const int lane = tid & 63;
    const int w    = tid >> 6;            // wave 0..3
    const int lr   = lane & 15;
    const int lk   = lane >> 4;           // 0..3
    const int r    = blockIdx.x;          // center range id (512 centers)
    const int qbase = blockIdx.y * 128 + w * 32;   // wave's 32 q rows
    const int rangeBase = r * 512;

    if (MODE == 1 && rangeBase >= N) return;       // pad ranges (cnt2 pre-zeroed)
    const int totChunks = N >> 5;                  // 3125 (N = 100000 exactly)
    const int ch0 = r * 16;
    const int nch = (MODE == 0) ? 16 : min(16, totChunks - ch0);

    // ---- resident A fragments: af[fm][ks] = 8 short8 = 32 VGPR ----
    short8 af[2][4];
    #pragma unroll
    for (int fm = 0; fm < 2; ++fm)
        #pragma unroll
        for (int ks = 0; ks < 4; ++ks)
            af[fm][ks] = *reinterpret_cast<const short8*>(
                Qb + (size_t)(qbase + fm * 16 + lr) * DDIM + (ks * 4 + lk) * 8);

    float thrv[2][4];
    if (MODE == 1) {
        #pragma unroll
        for (int fm = 0; fm < 2; ++fm)
            #pragma unroll
            for (int j = 0; j < 4; ++j)
                thrv[fm][j] = thr[qbase + fm * 16 + lk * 4 + j] - EPSM;
        if (lane < 32) off_l[w * 32 + lane] = 0;   // wave-private, no barrier
    }

// load one chunk's 8 B-fragments: lane-contiguous coalesced (frag f at
// chunk*4096 + f*512 shorts; per-lane 8 shorts at lane*8). f = ks*2+fn.
#define LOADBG(dst, cc) do {                                                   \
    const unsigned short* base_ = Kb + (size_t)(cc) * 4096 + lane * 8;         \
    _Pragma("unroll")                                                          \
    for (int ks_ = 0; ks_ < 4; ++ks_)                                          \
        _Pragma("unroll")                                                      \
        for (int fn_ = 0; fn_ < 2; ++fn_)                                      \
            dst[fn_][ks_] = *reinterpret_cast<const short8*>(                  \
                base_ + (ks_ * 2 + fn_) * 512);                                \
} while (0)

#define COMPUTE(bgX, tt) do {                                                  \
    const int cbase_ = rangeBase + (tt) * 32;                                  \
    const f32x4 z_ = {0.f, 0.f, 0.f, 0.f};                                     \
    f32x4 acc[2][2];                                                           \
    _Pragma("unroll")                                                          \
    for (int a_ = 0; a_ < 2; ++a_)                                             \
        _Pragma("unroll")                                                      \
        for (int b_ = 0; b_ < 2; ++b_) acc[a_][b_] = z_;                       \
    _Pragma("unroll")                                                          \
    for (int ks_ = 0; ks_ < 4; ++ks_)                                          \
        _Pragma("unroll")                                                      \
        for (int fm_ = 0; fm_ < 2; ++fm_)                                      \
            _Pragma("unroll")                                                  \
            for (int fn_ = 0; fn_ < 2; ++fn_)                                  \
                acc[fm_][fn_] = __builtin_amdgcn_mfma_f32_16x16x32_bf16(       \
                    af[fm_][ks_], bgX[fn_][ks_], acc[fm_][fn_], 0, 0, 0);      \
    /* epilogue — C/D map: col = lane&15, row = (lane>>4)*4 + reg [m89/m91] */ \
    _Pragma("unroll")                                                          \
    for (int fm_ = 0; fm_ < 2; ++fm_) {                                        \
        _Pragma("unroll")                                                      \
        for (int j_ = 0; j_ < 4; ++j_) {                                       \
            const int qlw = fm_ * 16 + lk * 4 + j_;   /* 0..31 within wave */  \
            if (MODE == 0) {                                                   \
                _Pragma("unroll")                                              \
                for (int fn_ = 0; fn_ < 2; ++fn_) {                            \
                    const int c_ = cbase_ + fn_ * 16 + lr;                     \
                    float s_ = acc[fm_][fn_][j_];                              \
                    int b_ = (int)((s_ + 0.5f) * 256.0f);  /* [-0.5,0.5] */    \
                    b_ = b_ < 0 ? 0 : (b_ > NBINS - 1 ? NBINS - 1 : b_);       \
                    binsU8[(size_t)(qbase + qlw) * MSAMPLE + c_] =             \
                        (unsigned char)b_;                                     \
                }                                                              \
            } else {                                                           \
                const float t_ = thrv[fm_][j_];                                \
                const float s0_ = acc[fm_][0][j_], s1_ = acc[fm_][1][j_];      \
                if (__any(fmaxf(s0_, s1_) >= t_)) {                            \
                    _Pragma("unroll")                                          \
                    for (int fn_ = 0; fn_ < 2; ++fn_) {                        \
                        const int c_ = cbase_ + fn_ * 16 + lr;                 \
                        const float s_ = fn_ ? s1_ : s0_;                      \
                        if (s_ >= t_) {   /* c_ < N always (exact chunks) */   \
                            int qs_ = (int)((s_ + 1.0f) * 16384.0f);           \
                            qs_ = qs_ < 0 ? 0 : (qs_ > 32767 ? 32767 : qs_);   \
                            unsigned key_ = ((unsigned)qs_ << QSH)             \
                                          | (~(unsigned)c_ & QMASK);           \
                            int p_ = atomicAdd(&off_l[w * 32 + qlw], 1);       \
                            if (p_ < BCAP)                                     \
                                buckets[((size_t)(qbase + qlw) * NGRP + r)     \
                                        * BCAP + p_] = key_;                   \
                        }                                                      \
                    }                                                          \
                }                                                              \
            }                                                                  \
        }                                                                      \
    }                                                                          \
} while (0)

    short8 bgA[2][4], bgB[2][4];
    LOADBG(bgA, ch0);
    int t = 0;
    for (; t + 2 <= nch; t += 2) {
        LOADBG(bgB, ch0 + t + 1);
        COMPUTE(bgA, t);
        if (t + 2 < nch) LOADBG(bgA, ch0 + t + 2);
        COMPUTE(bgB, t + 1);
    }
    if (t < nch) COMPUTE(bgA, t);          // odd tail (last range: 5 chunks)
#undef LOADBG
#undef COMPUTE

    if (MODE == 1) {
        if (lane < 32)
            cnt2[(size_t)(qbase + lane) * NGRP + r] =
                min(off_l[w * 32 + lane], BCAP);
    }
}

// ---------------------------------------------------------------------------
// thresh with per-wave sub-histograms; bins over [-0.5,0.5]
// ---------------------------------------------------------------------------
__global__ __launch_bounds__(256)
void thresh_kernel(const unsigned char* __restrict__ bins, float* __restrict__ thr)
{
    __shared__ int hS[4 * NBINS];
    __shared__ int hA[NBINS];
    __shared__ int hB[NBINS];
    __shared__ int best;
    const int q = blockIdx.x, tid = threadIdx.x;
    const int wv = tid >> 6;
    for (int i = tid; i < 4 * NBINS; i += 256) hS[i] = 0;
    if (tid == 0) best = 0;
    __syncthreads();
    const uint4* bp = reinterpret_cast<const uint4*>(bins + (size_t)q * MSAMPLE);
    int* hw = hS + wv * NBINS;
    for (int i = tid; i < MSAMPLE / 16; i += 256) {
        uint4 v = bp[i];
        unsigned xs[4] = {v.x, v.y, v.z, v.w};
        #pragma unroll
        for (int k = 0; k < 4; ++k) {
            unsigned x = xs[k];
            atomicAdd(&hw[x & 255], 1); x >>= 8;
            atomicAdd(&hw[x & 255], 1); x >>= 8;
            atomicAdd(&hw[x & 255], 1); x >>= 8;
            atomicAdd(&hw[x & 255], 1);
        }
    }
    __syncthreads();
    for (int i = tid; i < NBINS; i += 256)
        hA[i] = hS[i] + hS[NBINS + i] + hS[2 * NBINS + i] + hS[3 * NBINS + i];
    __syncthreads();
    int* src = hA; int* dst = hB;
    for (int off = 1; off < NBINS; off <<= 1) {
        for (int i = tid; i < NBINS; i += 256)
            dst[i] = src[i] + ((i + off < NBINS) ? src[i + off] : 0);
        __syncthreads();
        int* tmp = src; src = dst; dst = tmp;
    }
    for (int i = tid; i < NBINS; i += 256)
        if (src[i] >= TOPK) atomicMax(&best, i);
    __syncthreads();
    if (tid == 0)
        thr[q] = (float)(best - 1) * (1.0f / 256.0f) - 0.5f;   // lower edge - 1 bin
}

// ---------------------------------------------------------------------------
// Finalize: compact unsorted (200 groups, 4-wave hierarchical scan) ->
// 256-bin histogram rank-selection -> exact fp32 rbf for head set ->
// 256-wide u64 bitonic (rbf desc, idx asc = jax.lax.top_k) -> weights, gathers.
// ---------------------------------------------------------------------------
__global__ __launch_bounds__(256)
void finalize_kernel(const unsigned int* __restrict__ buckets, const int* __restrict__ cnt2,
                     const float* __restrict__ Qg, const float* __restrict__ Kg,
                     const float* __restrict__ V, const float* __restrict__ hIn,
                     const float* __restrict__ eIn,
                     float* __restrict__ out, int N)
{
    __shared__ float qv[DDIM];
    __shared__ unsigned sk[SORTN];
    __shared__ unsigned fk[FINEN];
    __shared__ unsigned long long sk64[FINEN];
    __shared__ int hA[NBINS];
    __shared__ int hB[NBINS];
    __shared__ int cnts[NGRP], offs[NGRP];
    __shared__ int wpart[4];
    __shared__ int bestb, nsel;
    __shared__ float selV[TOPK];
    __shared__ int   selI[TOPK];
    __shared__ float wts[TOPK];
    const int q = blockIdx.x, tid = threadIdx.x;

    if (tid < DDIM) qv[tid] = Qg[(size_t)q * DDIM + tid];
    if (tid < NGRP) cnts[tid] = cnt2[q * NGRP + tid];
    for (int i = tid; i < SORTN; i += 256) sk[i] = 0u;
    if (tid < NBINS) hA[tid] = 0;
    if (tid < FINEN) sk64[tid] = 0ull;
    if (tid == 0) { bestb = 0; nsel = 0; }
    __syncthreads();
    // 200-wide scan: per-wave (64) inclusive shfl scan + wave partial offsets
    int cv = 0, xv = 0;
    if (tid < NGRP) {
        cv = cnts[tid];
        xv = cv;
        #pragma unroll
        for (int o = 1; o < 64; o <<= 1) {
            int y = __shfl_up(xv, o);
            if ((tid & 63) >= o) xv += y;
        }
        if ((tid & 63) == 63) wpart[tid >> 6] = xv;   // tids 63,127,191
    }
    __syncthreads();
    if (tid < NGRP) {
        int add = 0;
        const int myw = tid >> 6;
        #pragma unroll
        for (int ww = 0; ww < 3; ++ww)
            if (ww < myw) add += wpart[ww];
        offs[tid] = xv - cv + add;
    }
    __syncthreads();
    for (int flat = tid; flat < NGRP * BCAP; flat += 256) {
        int gg = flat / BCAP, j = flat - gg * BCAP;
        if (j < cnts[gg]) {
            int dst = offs[gg] + j;
            if (dst < SORTN)
                sk[dst] = buckets[((size_t)q * NGRP + gg) * BCAP + j];
        }
    }
    __syncthreads();
    for (int i = tid; i < SORTN; i += 256) {
        unsigned k = sk[i];
        if (k) atomicAdd(&hA[k >> 24], 1);
    }
    __syncthreads();
    {
        int* src = hA; int* dst = hB;
        for (int off = 1; off < NBINS; off <<= 1) {
            for (int i = tid; i < NBINS; i += 256)
                dst[i] = src[i] + ((i + off < NBINS) ? src[i + off] : 0);
            __syncthreads();
            int* tmp = src; src = dst; dst = tmp;
        }
        for (int i = tid; i < NBINS; i += 256)
            if (src[i] >= TOPK) atomicMax(&bestb, i);
    }
    __syncthreads();
    const unsigned b32q = (unsigned)bestb << 7;
    const unsigned cutq = b32q > QMARGIN ? b32q - QMARGIN : 0u;
    const unsigned cutKey = cutq << QSH;
    for (int i = tid; i < SORTN; i += 256) {
        unsigned k = sk[i];
        if (k != 0u && k >= cutKey) {
            int p = atomicAdd(&nsel, 1);
            if (p < FINEN) fk[p] = k;
        }
    }
    __syncthreads();
    const int m = min(nsel, FINEN);
    const int sub = tid & 3, ci = tid >> 2;
    #pragma unroll
    for (int base = 0; base < FINEN; base += 64) {
        int i = base + ci;
        bool act = i < m;
        int c = 0;
        float s = 0.f;
        if (act) {
            c = (int)(~fk[i] & QMASK);
            const float4* k4 = reinterpret_cast<const float4*>(Kg + (size_t)c * DDIM) + sub;
            const float4* q4 = reinterpret_cast<const float4*>(qv) + sub;
            #pragma unroll
            for (int d = 0; d < 8; ++d) {
                float4 kk = k4[d * 4];
                float4 qq = q4[d * 4];
                s = fmaf(qq.x, kk.x, s); s = fmaf(qq.y, kk.y, s);
                s = fmaf(qq.z, kk.z, s); s = fmaf(qq.w, kk.w, s);
            }
        }
        s += __shfl_xor(s, 1); s += __shfl_xor(s, 2);
        if (act && sub == 0) {
            float dist = 2.0f - 2.0f * s;              // reference op order
            float rbf = expf(dist * -2.0f);            // exp(-dist/(2*0.25))
            sk64[i] = ((unsigned long long)__float_as_uint(rbf) << 32)
                    | (unsigned)(~(unsigned)c);        // rbf desc, then idx asc
        }
    }
    __syncthreads();
    for (int k = 2; k <= FINEN; k <<= 1) {
        for (int j = k >> 1; j > 0; j >>= 1) {
            int x = tid ^ j;
            if (x > tid) {
                unsigned long long a = sk64[tid], b = sk64[x];
                bool sw = ((tid & k) == 0) ? (a < b) : (a > b);
                if (sw) { sk64[tid] = b; sk64[x] = a; }
            }
            __syncthreads();
        }
    }
    if (tid < TOPK) {
        unsigned long long kk = sk64[tid];
        float rbf = __uint_as_float((unsigned)(kk >> 32));
        int   idx = (int)(~(unsigned)kk);
        selV[tid] = rbf; selI[tid] = idx;
        float lw = logf(rbf + 1e-8f) + logf(hIn[idx] + 1e-8f);
        float mx = lw;
        #pragma unroll
        for (int o = 16; o > 0; o >>= 1) mx = fmaxf(mx, __shfl_xor(mx, o));
        float ex = expf(lw - mx);
        float sm = ex;
        #pragma unroll
        for (int o = 16; o > 0; o >>= 1) sm += __shfl_xor(sm, o);
        wts[tid] = ex / sm;
    }
    __syncthreads();
    {
        float acc = 0.f;
        const int v = tid;
        #pragma unroll
        for (int k = 0; k < TOPK; ++k)
            acc = fmaf(wts[k], V[(size_t)selI[k] * 256 + v], acc);
        out[(size_t)q * 256 + v] = acc;
    }
    const int offE = NQTOT * 256;
    const int offW = offE + NQTOT * 4;
    const int offI = offW + NQTOT * TOPK;
    if (tid < 4) {
        float acc = 0.f;
        #pragma unroll
        for (int k = 0; k < TOPK; ++k)
            acc = fmaf(wts[k], eIn[(size_t)selI[k] * 4 + tid], acc);
        out[offE + q * 4 + tid] = acc;
    }
    if (tid < TOPK) {
        out[offW + q * TOPK + tid] = wts[tid];
        out[offI + q * TOPK + tid] = (float)selI[tid];
    }
}

// ---------------------------------------------------------------------------
extern "C" void kernel_launch(void* const* d_in, const int* in_sizes, int n_in,
                              void* d_out, int out_size, void* d_ws, size_t ws_size,
                              hipStream_t stream)
{
    (void)n_in; (void)out_size; (void)ws_size;
    const float* Qg = (const float*)d_in[0];
    const float* Kg = (const float*)d_in[1];
    const float* Vg = (const float*)d_in[2];
    const float* hg = (const float*)d_in[3];
    const float* eg = (const float*)d_in[4];
    const int N = in_sizes[1] / DDIM;          // 100000

    char* w = (char*)d_ws;
    unsigned short* Kbf = (unsigned short*)w;  w += (size_t)N * DDIM * 2;      // 25.6MB (fragment-major)
    unsigned short* Qbf = (unsigned short*)w;  w += (size_t)NQTOT * DDIM * 2;  // 256KB
    float* thr = (float*)w;                    w += NQTOT * 4;                 // 4KB
    int*   cnt2 = (int*)w;                     w += (size_t)NQTOT * NGRP * 4;  // 819KB
    unsigned char* binsU8 = (unsigned char*)w;                                 // 12.58MB
    unsigned int*  buckets = (unsigned int*)w; // aliases binsU8 (12.29MB used)

    hipMemsetAsync(cnt2, 0, (size_t)NQTOT * NGRP * 4, stream);

    dim3 blk(256);
    convert_kernel<<<dim3(2048), blk, 0, stream>>>(
        Qg, Kg, Qbf, Kbf, NQTOT * DDIM / 8, N * DDIM / 8);
    sim_pass<0><<<dim3(MSAMPLE / 512, NQTOT / 128), blk, 0, stream>>>(
        Qbf, Kbf, N, binsU8, nullptr, nullptr, nullptr);
    thresh_kernel<<<dim3(NQTOT), blk, 0, stream>>>(binsU8, thr);
    sim_pass<1><<<dim3(NGRP, NQTOT / 128), blk, 0, stream>>>(
        Qbf, Kbf, N, nullptr, thr, cnt2, buckets);
    finalize_kernel<<<dim3(NQTOT), blk, 0, stream>>>(
        buckets, cnt2, Qg, Kg, Vg, hg, eg, (float*)d_out, N);
}

// Round 23
// 123.507 us; speedup vs baseline: 1.1137x; 1.0050x over previous
//
#include <hip/hip_runtime.h>
#include <math.h>

// MemoryCenters: sim = q·K^T (1024x100000, D=128), top-32 by rbf=exp(-2*dist_sq),
// softmax(log(rbf+eps)+log(h+eps)), r_V = w·V_sel, r_E = w·e_sel.
//
// Round 23 = Round 22 (R19 reproduced: 124.1us) + T5 s_setprio(1) around the
// MFMA cluster in sim_pass. Catalog evidence: setprio is structure-conditional
// — hurts lockstep barrier GEMM (m190) but +4-7% on independent-wave kernels
// (m191). sim_pass MODE 1 is exactly the m191 regime: 4 independent waves,
// ZERO barriers in the main loop, waves at different chunk phases.
// Everything else byte-identical to R22.
// ws: 25.6MB Kbf + 256KB Qbf + 4KB thr + 819KB cnt2 + 12.58MB (binsU8|buckets).

#define DDIM    128
#define MSAMPLE 12288
#define NBINS   256
#define TOPK    32
#define NQTOT   1024
#define NGRP    200     // 196 real 512-center ranges + pad to multiple of 8
#define BCAP    15
#define EPSM    0.012f
#define SORTN   1024
#define FINEN   256
#define QSH     17
#define QMASK   0x1FFFFu
#define QMARGIN 200u    // 200/16384 = 0.0122 >= 2*EA(0.004) + 2 quanta

typedef __attribute__((ext_vector_type(8))) short short8;   // 8 bf16 = 4 VGPRs
typedef __attribute__((ext_vector_type(4))) float f32x4;    // mfma C/D frag

__device__ inline unsigned short f2bf(float f) {
    unsigned u = __builtin_bit_cast(unsigned, f);
    return (unsigned short)((u + 0x7FFFu + ((u >> 16) & 1u)) >> 16);
}

// ---------------------------------------------------------------------------
// convert: Q -> row-major bf16; K -> FRAGMENT-MAJOR bf16:
//   chunk = row>>5, fn = (row>>4)&1, lr = row&15, ks = m>>2, lk = m&3
//   dest shorts: chunk*4096 + (ks*2+fn)*512 + (lk*16+lr)*8
// ---------------------------------------------------------------------------
__global__ __launch_bounds__(256)
void convert_kernel(const float* __restrict__ Qg, const float* __restrict__ Kg,
                    unsigned short* __restrict__ Qbf, unsigned short* __restrict__ Kbf,
                    int nq8, int nk8)
{
    int total = nq8 + nk8;
    for (int i = blockIdx.x * 256 + threadIdx.x; i < total; i += gridDim.x * 256) {
        const float* s; int j;
        if (i < nq8) { s = Qg; j = i; }
        else         { s = Kg; j = i - nq8; }
        float4 a = *reinterpret_cast<const float4*>(s + (size_t)j * 8);
        float4 b = *reinterpret_cast<const float4*>(s + (size_t)j * 8 + 4);
        short8 o;
        o[0] = (short)f2bf(a.x); o[1] = (short)f2bf(a.y);
        o[2] = (short)f2bf(a.z); o[3] = (short)f2bf(a.w);
        o[4] = (short)f2bf(b.x); o[5] = (short)f2bf(b.y);
        o[6] = (short)f2bf(b.z); o[7] = (short)f2bf(b.w);
        if (i < nq8) {
            *reinterpret_cast<short8*>(Qbf + (size_t)j * 8) = o;
        } else {
            int row = j >> 4, m = j & 15;
            size_t dest = (size_t)(row >> 5) * 4096
                        + (size_t)((m >> 2) * 2 + ((row >> 4) & 1)) * 512
                        + (size_t)((m & 3) * 16 + (row & 15)) * 8;
            *reinterpret_cast<short8*>(Kbf + dest) = o;
        }
    }
}

// ---------------------------------------------------------------------------
// Barrier-free register-streaming bf16 MFMA sim pass (fragment-major Kbf).
// Wave = 32 q rows (af[2][4] resident) x one 512-center range (16 chunks),
// streamed as 8 coalesced 1KB fragment loads + 16 MFMA + epilogue per chunk.
// setprio(1) wraps the MFMA cluster (T5, independent-wave regime).
// MODE 0: u8 bins over [-0.5,0.5]. MODE 1: bucket-append packed keys.
// ---------------------------------------------------------------------------
template<int MODE>
__global__ __launch_bounds__(256)
void sim_pass(const unsigned short* __restrict__ Qb, const unsigned short* __restrict__ Kb,
              int N, unsigned char* __restrict__ binsU8,
              const float* __restrict__ thr,
              int* __restrict__ cnt2, unsigned int* __restrict__ buckets)
{
    __shared__ int off_l[128];            // 4 waves x 32 private counters
    const int tid  = threadIdx.x;
    const int lane = tid & 63;
    const int w    = tid >> 6;            // wave 0..3
    const int lr   = lane & 15;
    const int lk   = lane >> 4;           // 0..3
    const int r    = blockIdx.x;          // center range id (512 centers)
    const int qbase = blockIdx.y * 128 + w * 32;   // wave's 32 q rows
    const int rangeBase = r * 512;

    if (MODE == 1 && rangeBase >= N) return;       // pad ranges (cnt2 pre-zeroed)
    const int totChunks = N >> 5;                  // 3125 (N = 100000 exactly)
    const int ch0 = r * 16;
    const int nch = (MODE == 0) ? 16 : min(16, totChunks - ch0);

    // ---- resident A fragments: af[fm][ks] = 8 short8 = 32 VGPR ----
    short8 af[2][4];
    #pragma unroll
    for (int fm = 0; fm < 2; ++fm)
        #pragma unroll
        for (int ks = 0; ks < 4; ++ks)
            af[fm][ks] = *reinterpret_cast<const short8*>(
                Qb + (size_t)(qbase + fm * 16 + lr) * DDIM + (ks * 4 + lk) * 8);

    float thrv[2][4];
    if (MODE == 1) {
        #pragma unroll
        for (int fm = 0; fm < 2; ++fm)
            #pragma unroll
            for (int j = 0; j < 4; ++j)
                thrv[fm][j] = thr[qbase + fm * 16 + lk * 4 + j] - EPSM;
        if (lane < 32) off_l[w * 32 + lane] = 0;   // wave-private, no barrier
    }

// load one chunk's 8 B-fragments: lane-contiguous coalesced (frag f at
// chunk*4096 + f*512 shorts; per-lane 8 shorts at lane*8). f = ks*2+fn.
#define LOADBG(dst, cc) do {                                                   \
    const unsigned short* base_ = Kb + (size_t)(cc) * 4096 + lane * 8;         \
    _Pragma("unroll")                                                          \
    for (int ks_ = 0; ks_ < 4; ++ks_)                                          \
        _Pragma("unroll")                                                      \
        for (int fn_ = 0; fn_ < 2; ++fn_)                                      \
            dst[fn_][ks_] = *reinterpret_cast<const short8*>(                  \
                base_ + (ks_ * 2 + fn_) * 512);                                \
} while (0)

#define COMPUTE(bgX, tt) do {                                                  \
    const int cbase_ = rangeBase + (tt) * 32;                                  \
    const f32x4 z_ = {0.f, 0.f, 0.f, 0.f};                                     \
    f32x4 acc[2][2];                                                           \
    _Pragma("unroll")                                                          \
    for (int a_ = 0; a_ < 2; ++a_)                                             \
        _Pragma("unroll")                                                      \
        for (int b_ = 0; b_ < 2; ++b_) acc[a_][b_] = z_;                       \
    __builtin_amdgcn_s_setprio(1);   /* T5: favor MFMA-ready wave */           \
    _Pragma("unroll")                                                          \
    for (int ks_ = 0; ks_ < 4; ++ks_)                                          \
        _Pragma("unroll")                                                      \
        for (int fm_ = 0; fm_ < 2; ++fm_)                                      \
            _Pragma("unroll")                                                  \
            for (int fn_ = 0; fn_ < 2; ++fn_)                                  \
                acc[fm_][fn_] = __builtin_amdgcn_mfma_f32_16x16x32_bf16(       \
                    af[fm_][ks_], bgX[fn_][ks_], acc[fm_][fn_], 0, 0, 0);      \
    __builtin_amdgcn_s_setprio(0);                                             \
    /* epilogue — C/D map: col = lane&15, row = (lane>>4)*4 + reg [m89/m91] */ \
    _Pragma("unroll")                                                          \
    for (int fm_ = 0; fm_ < 2; ++fm_) {                                        \
        _Pragma("unroll")                                                      \
        for (int j_ = 0; j_ < 4; ++j_) {                                       \
            const int qlw = fm_ * 16 + lk * 4 + j_;   /* 0..31 within wave */  \
            if (MODE == 0) {                                                   \
                _Pragma("unroll")                                              \
                for (int fn_ = 0; fn_ < 2; ++fn_) {                            \
                    const int c_ = cbase_ + fn_ * 16 + lr;                     \
                    float s_ = acc[fm_][fn_][j_];                              \
                    int b_ = (int)((s_ + 0.5f) * 256.0f);  /* [-0.5,0.5] */    \
                    b_ = b_ < 0 ? 0 : (b_ > NBINS - 1 ? NBINS - 1 : b_);       \
                    binsU8[(size_t)(qbase + qlw) * MSAMPLE + c_] =             \
                        (unsigned char)b_;                                     \
                }                                                              \
            } else {                                                           \
                const float t_ = thrv[fm_][j_];                                \
                const float s0_ = acc[fm_][0][j_], s1_ = acc[fm_][1][j_];      \
                if (__any(fmaxf(s0_, s1_) >= t_)) {                            \
                    _Pragma("unroll")                                          \
                    for (int fn_ = 0; fn_ < 2; ++fn_) {                        \
                        const int c_ = cbase_ + fn_ * 16 + lr;                 \
                        const float s_ = fn_ ? s1_ : s0_;                      \
                        if (s_ >= t_) {   /* c_ < N always (exact chunks) */   \
                            int qs_ = (int)((s_ + 1.0f) * 16384.0f);           \
                            qs_ = qs_ < 0 ? 0 : (qs_ > 32767 ? 32767 : qs_);   \
                            unsigned key_ = ((unsigned)qs_ << QSH)             \
                                          | (~(unsigned)c_ & QMASK);           \
                            int p_ = atomicAdd(&off_l[w * 32 + qlw], 1);       \
                            if (p_ < BCAP)                                     \
                                buckets[((size_t)(qbase + qlw) * NGRP + r)     \
                                        * BCAP + p_] = key_;                   \
                        }                                                      \
                    }                                                          \
                }                                                              \
            }                                                                  \
        }                                                                      \
    }                                                                          \
} while (0)

    short8 bgA[2][4], bgB[2][4];
    LOADBG(bgA, ch0);
    int t = 0;
    for (; t + 2 <= nch; t += 2) {
        LOADBG(bgB, ch0 + t + 1);
        COMPUTE(bgA, t);
        if (t + 2 < nch) LOADBG(bgA, ch0 + t + 2);
        COMPUTE(bgB, t + 1);
    }
    if (t < nch) COMPUTE(bgA, t);          // odd tail (last range: 5 chunks)
#undef LOADBG
#undef COMPUTE

    if (MODE == 1) {
        if (lane < 32)
            cnt2[(size_t)(qbase + lane) * NGRP + r] =
                min(off_l[w * 32 + lane], BCAP);
    }
}

// ---------------------------------------------------------------------------
// thresh with per-wave sub-histograms; bins over [-0.5,0.5]
// ---------------------------------------------------------------------------
__global__ __launch_bounds__(256)
void thresh_kernel(const unsigned char* __restrict__ bins, float* __restrict__ thr)
{
    __shared__ int hS[4 * NBINS];
    __shared__ int hA[NBINS];
    __shared__ int hB[NBINS];
    __shared__ int best;
    const int q = blockIdx.x, tid = threadIdx.x;
    const int wv = tid >> 6;
    for (int i = tid; i < 4 * NBINS; i += 256) hS[i] = 0;
    if (tid == 0) best = 0;
    __syncthreads();
    const uint4* bp = reinterpret_cast<const uint4*>(bins + (size_t)q * MSAMPLE);
    int* hw = hS + wv * NBINS;
    for (int i = tid; i < MSAMPLE / 16; i += 256) {
        uint4 v = bp[i];
        unsigned xs[4] = {v.x, v.y, v.z, v.w};
        #pragma unroll
        for (int k = 0; k < 4; ++k) {
            unsigned x = xs[k];
            atomicAdd(&hw[x & 255], 1); x >>= 8;
            atomicAdd(&hw[x & 255], 1); x >>= 8;
            atomicAdd(&hw[x & 255], 1); x >>= 8;
            atomicAdd(&hw[x & 255], 1);
        }
    }
    __syncthreads();
    for (int i = tid; i < NBINS; i += 256)
        hA[i] = hS[i] + hS[NBINS + i] + hS[2 * NBINS + i] + hS[3 * NBINS + i];
    __syncthreads();
    int* src = hA; int* dst = hB;
    for (int off = 1; off < NBINS; off <<= 1) {
        for (int i = tid; i < NBINS; i += 256)
            dst[i] = src[i] + ((i + off < NBINS) ? src[i + off] : 0);
        __syncthreads();
        int* tmp = src; src = dst; dst = tmp;
    }
    for (int i = tid; i < NBINS; i += 256)
        if (src[i] >= TOPK) atomicMax(&best, i);
    __syncthreads();
    if (tid == 0)
        thr[q] = (float)(best - 1) * (1.0f / 256.0f) - 0.5f;   // lower edge - 1 bin
}

// ---------------------------------------------------------------------------
// Finalize: compact unsorted (200 groups, 4-wave hierarchical scan) ->
// 256-bin histogram rank-selection -> exact fp32 rbf for head set ->
// 256-wide u64 bitonic (rbf desc, idx asc = jax.lax.top_k) -> weights, gathers.
// ---------------------------------------------------------------------------
__global__ __launch_bounds__(256)
void finalize_kernel(const unsigned int* __restrict__ buckets, const int* __restrict__ cnt2,
                     const float* __restrict__ Qg, const float* __restrict__ Kg,
                     const float* __restrict__ V, const float* __restrict__ hIn,
                     const float* __restrict__ eIn,
                     float* __restrict__ out, int N)
{
    __shared__ float qv[DDIM];
    __shared__ unsigned sk[SORTN];
    __shared__ unsigned fk[FINEN];
    __shared__ unsigned long long sk64[FINEN];
    __shared__ int hA[NBINS];
    __shared__ int hB[NBINS];
    __shared__ int cnts[NGRP], offs[NGRP];
    __shared__ int wpart[4];
    __shared__ int bestb, nsel;
    __shared__ float selV[TOPK];
    __shared__ int   selI[TOPK];
    __shared__ float wts[TOPK];
    const int q = blockIdx.x, tid = threadIdx.x;

    if (tid < DDIM) qv[tid] = Qg[(size_t)q * DDIM + tid];
    if (tid < NGRP) cnts[tid] = cnt2[q * NGRP + tid];
    for (int i = tid; i < SORTN; i += 256) sk[i] = 0u;
    if (tid < NBINS) hA[tid] = 0;
    if (tid < FINEN) sk64[tid] = 0ull;
    if (tid == 0) { bestb = 0; nsel = 0; }
    __syncthreads();
    // 200-wide scan: per-wave (64) inclusive shfl scan + wave partial offsets
    int cv = 0, xv = 0;
    if (tid < NGRP) {
        cv = cnts[tid];
        xv = cv;
        #pragma unroll
        for (int o = 1; o < 64; o <<= 1) {
            int y = __shfl_up(xv, o);
            if ((tid & 63) >= o) xv += y;
        }
        if ((tid & 63) == 63) wpart[tid >> 6] = xv;   // tids 63,127,191
    }
    __syncthreads();
    if (tid < NGRP) {
        int add = 0;
        const int myw = tid >> 6;
        #pragma unroll
        for (int ww = 0; ww < 3; ++ww)
            if (ww < myw) add += wpart[ww];
        offs[tid] = xv - cv + add;
    }
    __syncthreads();
    for (int flat = tid; flat < NGRP * BCAP; flat += 256) {
        int gg = flat / BCAP, j = flat - gg * BCAP;
        if (j < cnts[gg]) {
            int dst = offs[gg] + j;
            if (dst < SORTN)
                sk[dst] = buckets[((size_t)q * NGRP + gg) * BCAP + j];
        }
    }
    __syncthreads();
    for (int i = tid; i < SORTN; i += 256) {
        unsigned k = sk[i];
        if (k) atomicAdd(&hA[k >> 24], 1);
    }
    __syncthreads();
    {
        int* src = hA; int* dst = hB;
        for (int off = 1; off < NBINS; off <<= 1) {
            for (int i = tid; i < NBINS; i += 256)
                dst[i] = src[i] + ((i + off < NBINS) ? src[i + off] : 0);
            __syncthreads();
            int* tmp = src; src = dst; dst = tmp;
        }
        for (int i = tid; i < NBINS; i += 256)
            if (src[i] >= TOPK) atomicMax(&bestb, i);
    }
    __syncthreads();
    const unsigned b32q = (unsigned)bestb << 7;
    const unsigned cutq = b32q > QMARGIN ? b32q - QMARGIN : 0u;
    const unsigned cutKey = cutq << QSH;
    for (int i = tid; i < SORTN; i += 256) {
        unsigned k = sk[i];
        if (k != 0u && k >= cutKey) {
            int p = atomicAdd(&nsel, 1);
            if (p < FINEN) fk[p] = k;
        }
    }
    __syncthreads();
    const int m = min(nsel, FINEN);
    const int sub = tid & 3, ci = tid >> 2;
    #pragma unroll
    for (int base = 0; base < FINEN; base += 64) {
        int i = base + ci;
        bool act = i < m;
        int c = 0;
        float s = 0.f;
        if (act) {
            c = (int)(~fk[i] & QMASK);
            const float4* k4 = reinterpret_cast<const float4*>(Kg + (size_t)c * DDIM) + sub;
            const float4* q4 = reinterpret_cast<const float4*>(qv) + sub;
            #pragma unroll
            for (int d = 0; d < 8; ++d) {
                float4 kk = k4[d * 4];
                float4 qq = q4[d * 4];
                s = fmaf(qq.x, kk.x, s); s = fmaf(qq.y, kk.y, s);
                s = fmaf(qq.z, kk.z, s); s = fmaf(qq.w, kk.w, s);
            }
        }
        s += __shfl_xor(s, 1); s += __shfl_xor(s, 2);
        if (act && sub == 0) {
            float dist = 2.0f - 2.0f * s;              // reference op order
            float rbf = expf(dist * -2.0f);            // exp(-dist/(2*0.25))
            sk64[i] = ((unsigned long long)__float_as_uint(rbf) << 32)
                    | (unsigned)(~(unsigned)c);        // rbf desc, then idx asc
        }
    }
    __syncthreads();
    for (int k = 2; k <= FINEN; k <<= 1) {
        for (int j = k >> 1; j > 0; j >>= 1) {
            int x = tid ^ j;
            if (x > tid) {
                unsigned long long a = sk64[tid], b = sk64[x];
                bool sw = ((tid & k) == 0) ? (a < b) : (a > b);
                if (sw) { sk64[tid] = b; sk64[x] = a; }
            }
            __syncthreads();
        }
    }
    if (tid < TOPK) {
        unsigned long long kk = sk64[tid];
        float rbf = __uint_as_float((unsigned)(kk >> 32));
        int   idx = (int)(~(unsigned)kk);
        selV[tid] = rbf; selI[tid] = idx;
        float lw = logf(rbf + 1e-8f) + logf(hIn[idx] + 1e-8f);
        float mx = lw;
        #pragma unroll
        for (int o = 16; o > 0; o >>= 1) mx = fmaxf(mx, __shfl_xor(mx, o));
        float ex = expf(lw - mx);
        float sm = ex;
        #pragma unroll
        for (int o = 16; o > 0; o >>= 1) sm += __shfl_xor(sm, o);
        wts[tid] = ex / sm;
    }
    __syncthreads();
    {
        float acc = 0.f;
        const int v = tid;
        #pragma unroll
        for (int k = 0; k < TOPK; ++k)
            acc = fmaf(wts[k], V[(size_t)selI[k] * 256 + v], acc);
        out[(size_t)q * 256 + v] = acc;
    }
    const int offE = NQTOT * 256;
    const int offW = offE + NQTOT * 4;
    const int offI = offW + NQTOT * TOPK;
    if (tid < 4) {
        float acc = 0.f;
        #pragma unroll
        for (int k = 0; k < TOPK; ++k)
            acc = fmaf(wts[k], eIn[(size_t)selI[k] * 4 + tid], acc);
        out[offE + q * 4 + tid] = acc;
    }
    if (tid < TOPK) {
        out[offW + q * TOPK + tid] = wts[tid];
        out[offI + q * TOPK + tid] = (float)selI[tid];
    }
}

// ---------------------------------------------------------------------------
extern "C" void kernel_launch(void* const* d_in, const int* in_sizes, int n_in,
                              void* d_out, int out_size, void* d_ws, size_t ws_size,
                              hipStream_t stream)
{
    (void)n_in; (void)out_size; (void)ws_size;
    const float* Qg = (const float*)d_in[0];
    const float* Kg = (const float*)d_in[1];
    const float* Vg = (const float*)d_in[2];
    const float* hg = (const float*)d_in[3];
    const float* eg = (const float*)d_in[4];
    const int N = in_sizes[1] / DDIM;          // 100000

    char* w = (char*)d_ws;
    unsigned short* Kbf = (unsigned short*)w;  w += (size_t)N * DDIM * 2;      // 25.6MB (fragment-major)
    unsigned short* Qbf = (unsigned short*)w;  w += (size_t)NQTOT * DDIM * 2;  // 256KB
    float* thr = (float*)w;                    w += NQTOT * 4;                 // 4KB
    int*   cnt2 = (int*)w;                     w += (size_t)NQTOT * NGRP * 4;  // 819KB
    unsigned char* binsU8 = (unsigned char*)w;                                 // 12.58MB
    unsigned int*  buckets = (unsigned int*)w; // aliases binsU8 (12.29MB used)

    hipMemsetAsync(cnt2, 0, (size_t)NQTOT * NGRP * 4, stream);

    dim3 blk(256);
    convert_kernel<<<dim3(2048), blk, 0, stream>>>(
        Qg, Kg, Qbf, Kbf, NQTOT * DDIM / 8, N * DDIM / 8);
    sim_pass<0><<<dim3(MSAMPLE / 512, NQTOT / 128), blk, 0, stream>>>(
        Qbf, Kbf, N, binsU8, nullptr, nullptr, nullptr);
    thresh_kernel<<<dim3(NQTOT), blk, 0, stream>>>(binsU8, thr);
    sim_pass<1><<<dim3(NGRP, NQTOT / 128), blk, 0, stream>>>(
        Qbf, Kbf, N, nullptr, thr, cnt2, buckets);
    finalize_kernel<<<dim3(NQTOT), blk, 0, stream>>>(
        buckets, cnt2, Qg, Kg, Vg, hg, eg, (float*)d_out, N);
}